// Round 1
// baseline (1324.559 us; speedup 1.0000x reference)
//
#include <hip/hip_runtime.h>
#include <hip/hip_bf16.h>
#include <stdint.h>

#define HIDDEN 1024
#define FEAT   512
#define PREV   10
#define PRED   20
#define BATCH  1024
#define KTOT   (HIDDEN + FEAT)   // 1536
#define N4H    4096

typedef __attribute__((ext_vector_type(8))) short short8;
typedef __attribute__((ext_vector_type(4))) float f32x4;

// ---- async global->LDS 16B copy (wave-uniform LDS base + lane*16) ----
typedef __attribute__((address_space(3))) unsigned int u32_lds;
typedef const __attribute__((address_space(1))) unsigned int u32_gbl;

__device__ __forceinline__ void async16(void* lds, const void* g) {
  u32_lds* lp = (u32_lds*)(unsigned int)(uintptr_t)lds;
  u32_gbl* gp = (u32_gbl*)(uintptr_t)g;
  __builtin_amdgcn_global_load_lds(gp, lp, 16, 0, 0);
}

__device__ __forceinline__ float sigmoidf_(float x) {
  return 1.0f / (1.0f + __expf(-x));
}
__device__ __forceinline__ float tanhf_(float x) {
  return 1.0f - 2.0f / (1.0f + __expf(2.0f * x));
}

// ---- pack [Wh;Wx] (fp32, [K,4096] gate-blocked) -> WpT (bf16, [4096,K], gate-interleaved n=4j+g) ----
__global__ void pack_w_kernel(const float* __restrict__ Wx, const float* __restrict__ Wh,
                              __hip_bfloat16* __restrict__ WpT) {
  __shared__ float tile[64][65];
  const int k0 = blockIdx.x * 64, n0 = blockIdx.y * 64;
  const int tid = threadIdx.x;
  const float* src = (k0 < HIDDEN) ? (Wh + (size_t)k0 * N4H) : (Wx + (size_t)(k0 - HIDDEN) * N4H);
  {
    const int jl = tid & 15, g = (tid >> 4) & 3, klb = tid >> 6;
#pragma unroll
    for (int it = 0; it < 16; ++it) {
      int kl = klb + it * 4;
      tile[kl][4 * jl + g] = src[(size_t)kl * N4H + g * HIDDEN + (n0 >> 2) + jl];
    }
  }
  __syncthreads();
  {
    const int kl = tid & 63, nlb = tid >> 6;
#pragma unroll
    for (int it = 0; it < 16; ++it) {
      int nl = nlb + it * 4;
      WpT[(size_t)(n0 + nl) * KTOT + k0 + kl] = __float2bfloat16(tile[kl][nl]);
    }
  }
}

__global__ void pack_bias_kernel(const float* __restrict__ b, float* __restrict__ bp) {
  int n = blockIdx.x * 256 + threadIdx.x;
  if (n < N4H) bp[n] = b[(n & 3) * HIDDEN + (n >> 2)];
}

// ---- convert inputs fp32 -> bf16 ----
__global__ void cvt_x_kernel(const float* __restrict__ xr, const float* __restrict__ xf,
                             __hip_bfloat16* __restrict__ xrb, __hip_bfloat16* __restrict__ xfb) {
  const int NR4 = BATCH * (PREV + PRED) * FEAT / 4;  // 3932160
  const int NF4 = BATCH * PRED * FEAT / 4;           // 2621440
  int i = blockIdx.x * 256 + threadIdx.x;
  float4 v;
  __hip_bfloat16* dst;
  if (i < NR4) {
    v = ((const float4*)xr)[i];
    dst = xrb + (size_t)i * 4;
  } else {
    int j = i - NR4;
    if (j >= NF4) return;
    v = ((const float4*)xf)[j];
    dst = xfb + (size_t)j * 4;
  }
  dst[0] = __float2bfloat16(v.x);
  dst[1] = __float2bfloat16(v.y);
  dst[2] = __float2bfloat16(v.z);
  dst[3] = __float2bfloat16(v.w);
}

// ---- one LSTM timestep: z = [h;x_t]@[Wh;Wx]^packed + b, gates, c/h update, fused h.w2 dot ----
// grid: (32 n-tiles, rowTiles). block 256 = 4 waves, each wave 64x64 quadrant of 128x128 tile.
__global__ __launch_bounds__(256, 2)
void lstm_step_kernel(const __hip_bfloat16* __restrict__ hcur,
                      __hip_bfloat16* __restrict__ hnext,
                      const __hip_bfloat16* __restrict__ xrb,
                      const __hip_bfloat16* __restrict__ xfb,
                      const __hip_bfloat16* __restrict__ WpT,
                      const float* __restrict__ biasp,
                      const float* __restrict__ w2,
                      float* __restrict__ cbuf,
                      float* __restrict__ accout,
                      int t, int do_out) {
  __shared__ __align__(16) char smem[65536];  // staging: A[0,16K) B[16K,32K); epilogue: z 128x128 f32
  const int tid = threadIdx.x;
  const int n0 = blockIdx.x * 128;
  const int r0 = blockIdx.y * 128;
  const int w = tid >> 6, l = tid & 63;
  const int sub = l >> 3;                 // == (row&7) for staged rows
  const int csrc = (l & 7) ^ sub;         // swizzled source 16B-column
  const int quad = l >> 4, lrow = l & 15;
  const int wm = w >> 1, wn = w & 1;

  f32x4 acc[4][4];
#pragma unroll
  for (int a = 0; a < 4; ++a)
#pragma unroll
    for (int bb = 0; bb < 4; ++bb) acc[a][bb] = (f32x4){0.f, 0.f, 0.f, 0.f};

  const __hip_bfloat16* bbase0 = WpT + (size_t)n0 * KTOT;

  for (int kt = 0; kt < KTOT / 64; ++kt) {
    const int k0 = kt * 64;
    // --- stage A tile [128 rows x 64 k] (source: h for k<1024, x_t else) ---
    const __hip_bfloat16* abase;
    int astr;
    if (k0 < HIDDEN) {
      abase = hcur + (size_t)r0 * HIDDEN + k0;
      astr = HIDDEN;
    } else if (r0 < BATCH) {
      abase = xrb + ((size_t)r0 * (PREV + PRED) + t) * FEAT + (k0 - HIDDEN);
      astr = (PREV + PRED) * FEAT;
    } else {
      abase = xfb + ((size_t)(r0 - BATCH) * PRED + (t - PREV)) * FEAT + (k0 - HIDDEN);
      astr = PRED * FEAT;
    }
#pragma unroll
    for (int it = 0; it < 4; ++it) {
      int row = it * 32 + w * 8 + sub;
      async16(smem + (it * 32 + w * 8) * 128, abase + (size_t)row * astr + csrc * 8);
    }
    // --- stage B tile [128 n x 64 k] from WpT (n-major) ---
    const __hip_bfloat16* bbase = bbase0 + k0;
#pragma unroll
    for (int it = 0; it < 4; ++it) {
      int row = it * 32 + w * 8 + sub;
      async16(smem + 16384 + (it * 32 + w * 8) * 128, bbase + (size_t)row * KTOT + csrc * 8);
    }
    __syncthreads();
#pragma unroll
    for (int kk = 0; kk < 2; ++kk) {
      const int swz = (((kk << 2) + quad) ^ (lrow & 7)) * 16;
      short8 af[4], bf[4];
#pragma unroll
      for (int mi = 0; mi < 4; ++mi)
        af[mi] = *(const short8*)(smem + (wm * 64 + mi * 16 + lrow) * 128 + swz);
#pragma unroll
      for (int ni = 0; ni < 4; ++ni)
        bf[ni] = *(const short8*)(smem + 16384 + (wn * 64 + ni * 16 + lrow) * 128 + swz);
#pragma unroll
      for (int mi = 0; mi < 4; ++mi)
#pragma unroll
        for (int ni = 0; ni < 4; ++ni)
          acc[mi][ni] = __builtin_amdgcn_mfma_f32_16x16x32_bf16(af[mi], bf[ni], acc[mi][ni], 0, 0, 0);
    }
    __syncthreads();
  }

  // --- epilogue: z tile -> LDS, then gate fusion ---
  float* zb = (float*)smem;
#pragma unroll
  for (int mi = 0; mi < 4; ++mi) {
    int rb = wm * 64 + mi * 16 + quad * 4;
#pragma unroll
    for (int ni = 0; ni < 4; ++ni) {
      int cb = wn * 64 + ni * 16 + lrow;
      f32x4 v = acc[mi][ni];
#pragma unroll
      for (int r = 0; r < 4; ++r) zb[(rb + r) * 128 + cb] = v[r];
    }
  }
  __syncthreads();

  const int jbase = n0 >> 2;
  const int kout = t - PREV;
#pragma unroll
  for (int it = 0; it < 16; ++it) {
    int idx = tid + it * 256;
    int row = idx >> 5, j = idx & 31;  // lanes [0..31] of a wave share a row
    float4 z4 = *(float4*)&zb[row * 128 + j * 4];
    float4 bi = *(const float4*)&biasp[n0 + j * 4];
    float gi = sigmoidf_(z4.x + bi.x);
    float gf = sigmoidf_(z4.y + bi.y);
    float gg = tanhf_(z4.z + bi.z);
    float go = sigmoidf_(z4.w + bi.w);
    int rg = r0 + row, jg = jbase + j;
    size_t cidx = (size_t)rg * HIDDEN + jg;
    float cold = cbuf[cidx];
    float cnew = gf * cold + gi * gg;
    float hnew = go * tanhf_(cnew);
    cbuf[cidx] = cnew;
    hnext[cidx] = __float2bfloat16(hnew);
    if (do_out) {
      float p = hnew * w2[jg];
#pragma unroll
      for (int off = 16; off > 0; off >>= 1) p += __shfl_down(p, off, 32);
      if ((tid & 31) == 0) atomicAdd(&accout[rg * PRED + kout], p);
    }
  }
}

// ---- final tanh chain over the 40960 fused dots ----
__global__ void final_kernel(const float* __restrict__ accout, const float* __restrict__ b2,
                             const float* __restrict__ w3, const float* __restrict__ b3,
                             const float* __restrict__ w4, const float* __restrict__ b4,
                             float* __restrict__ out) {
  int i = blockIdx.x * 256 + threadIdx.x;
  const int half = BATCH * PRED;
  if (i >= 2 * half) return;
  int r, k;
  if (i < half) {
    r = i / PRED;
    k = i % PRED;
  } else {
    r = BATCH + (i - half) / PRED;
    k = (i - half) % PRED;
  }
  float x = tanhf_(accout[r * PRED + k] + b2[0]);
  x = tanhf_(x * w3[0] + b3[0]);
  x = tanhf_(x * w4[0] + b4[0]);
  out[i] = x;
}

extern "C" void kernel_launch(void* const* d_in, const int* in_sizes, int n_in,
                              void* d_out, int out_size, void* d_ws, size_t ws_size,
                              hipStream_t stream) {
  const float* real_input = (const float*)d_in[0];
  const float* fake_input = (const float*)d_in[1];
  const float* Wx = (const float*)d_in[2];
  const float* Wh = (const float*)d_in[3];
  const float* b  = (const float*)d_in[4];
  const float* w2 = (const float*)d_in[5];
  const float* b2 = (const float*)d_in[6];
  const float* w3 = (const float*)d_in[7];
  const float* b3 = (const float*)d_in[8];
  const float* w4 = (const float*)d_in[9];
  const float* b4 = (const float*)d_in[10];
  float* out = (float*)d_out;

  char* ws = (char*)d_ws;
  size_t off = 0;
  __hip_bfloat16* WpT = (__hip_bfloat16*)(ws + off);  off += (size_t)N4H * KTOT * 2;        // 12.6 MB
  float* biasp = (float*)(ws + off);                  off += (size_t)N4H * 4;               // 16 KB
  __hip_bfloat16* xrb = (__hip_bfloat16*)(ws + off);  off += (size_t)BATCH * 30 * FEAT * 2; // 31.5 MB
  __hip_bfloat16* xfb = (__hip_bfloat16*)(ws + off);  off += (size_t)BATCH * 20 * FEAT * 2; // 21 MB
  __hip_bfloat16* h0 = (__hip_bfloat16*)(ws + off);   off += (size_t)2 * BATCH * HIDDEN * 2;// 4 MB
  __hip_bfloat16* h1 = (__hip_bfloat16*)(ws + off);   off += (size_t)2 * BATCH * HIDDEN * 2;// 4 MB
  float* cbuf = (float*)(ws + off);                   off += (size_t)2 * BATCH * HIDDEN * 4;// 8 MB
  float* accout = (float*)(ws + off);                 off += (size_t)2 * BATCH * PRED * 4;  // 160 KB

  hipMemsetAsync(h0, 0, (size_t)2 * BATCH * HIDDEN * 2, stream);
  hipMemsetAsync(cbuf, 0, (size_t)2 * BATCH * HIDDEN * 4, stream);
  hipMemsetAsync(accout, 0, (size_t)2 * BATCH * PRED * 4, stream);

  pack_w_kernel<<<dim3(KTOT / 64, N4H / 64), 256, 0, stream>>>(Wx, Wh, WpT);
  pack_bias_kernel<<<N4H / 256, 256, 0, stream>>>(b, biasp);
  {
    int n4 = BATCH * 30 * FEAT / 4 + BATCH * 20 * FEAT / 4;
    cvt_x_kernel<<<(n4 + 255) / 256, 256, 0, stream>>>(real_input, fake_input, xrb, xfb);
  }

  __hip_bfloat16* hb[2] = {h0, h1};
  // shared prefix, B=1024
  for (int t = 0; t < PREV; ++t) {
    lstm_step_kernel<<<dim3(N4H / 128, BATCH / 128), 256, 0, stream>>>(
        hb[t & 1], hb[(t + 1) & 1], xrb, xfb, WpT, biasp, w2, cbuf, accout, t, 0);
  }
  // fork state: copy rows [0,1024) -> [1024,2048) of h and c
  {
    __hip_bfloat16* hs = hb[PREV & 1];
    hipMemcpyAsync(hs + (size_t)BATCH * HIDDEN, hs, (size_t)BATCH * HIDDEN * 2,
                   hipMemcpyDeviceToDevice, stream);
    hipMemcpyAsync(cbuf + (size_t)BATCH * HIDDEN, cbuf, (size_t)BATCH * HIDDEN * 4,
                   hipMemcpyDeviceToDevice, stream);
  }
  // main phase, B_eff=2048 (real || fake)
  for (int t = PREV; t < PREV + PRED; ++t) {
    lstm_step_kernel<<<dim3(N4H / 128, 2 * BATCH / 128), 256, 0, stream>>>(
        hb[t & 1], hb[(t + 1) & 1], xrb, xfb, WpT, biasp, w2, cbuf, accout, t, 1);
  }
  final_kernel<<<(2 * BATCH * PRED + 255) / 256, 256, 0, stream>>>(accout, b2, w3, b3, w4, b4, out);
}